// Round 1
// 306.617 us; speedup vs baseline: 1.0362x; 1.0362x over previous
//
#include <hip/hip_runtime.h>
#include <hip/hip_bf16.h>

// SimpleFuzzyAttention: B=2, S=2048, D=1024, H=16, DK=64
// fz(s) is univariate -> packed-pair bf16 LUT of g(s)=exp(fz(s)-max);
// attention = 1-gather LUT lerp + un-normalized softmax. bf16 MFMA GEMMs.
// R5: flash rewritten to 32x32x16 MFMA with in-register P (T12): swapped
// QK^T (S^T = K.Q^T) puts P rows lane-local; v_cvt_pk_bf16_f32 +
// v_permlane32_swap_b32 build the PV B-fragments with NO Ps LDS round-trip.
// Wave = 32q x 32kv quadrant; per-wave-tile LDS ops drop 585 -> ~224 cy.
// GEMMs / prep / LUT unchanged from R4.

#define S_LEN 2048
#define DMODEL 1024
#define NHEAD 16
#define DKH 64
#define NLUT 2048
#define LUT_MIN (-10.0f)
#define LUT_MAX (10.0f)

typedef __attribute__((ext_vector_type(8))) short bfx8;   // 8 bf16 (4 VGPRs)
typedef __attribute__((ext_vector_type(4))) float fx4;    // MFMA C/D 16x16
typedef __attribute__((ext_vector_type(16))) float fx16;  // MFMA C/D 32x32
typedef __attribute__((ext_vector_type(4))) unsigned ux4;

__device__ __forceinline__ short f2bf(float x) {
    unsigned u = __builtin_bit_cast(unsigned, x);
    u = (u + 0x7fffu + ((u >> 16) & 1u)) >> 16;   // RNE
    return (short)u;
}

__device__ __forceinline__ unsigned cvt_pk_bf16(float lo, float hi) {
    unsigned r;
    asm("v_cvt_pk_bf16_f32 %0, %1, %2" : "=v"(r) : "v"(lo), "v"(hi));
    return r;
}

// v_permlane32_swap_b32: exchanges high 32 lanes of arg a with low 32 lanes
// of arg b (T12 convention: first arg = lower-kv pair, keeps its low lanes).
// After: a = {a_lo, b_lo}, b = {a_hi, b_hi}.
__device__ __forceinline__ void plane_swap(unsigned& a, unsigned& b) {
    asm volatile("v_permlane32_swap_b32 %0, %1" : "+v"(a), "+v"(b));
}

__device__ __forceinline__ void stage8_f32(const float* __restrict__ src, short* dst) {
    float4 a = *(const float4*)(src);
    float4 b = *(const float4*)(src + 4);
    bfx8 r;
    r[0] = f2bf(a.x); r[1] = f2bf(a.y); r[2] = f2bf(a.z); r[3] = f2bf(a.w);
    r[4] = f2bf(b.x); r[5] = f2bf(b.y); r[6] = f2bf(b.z); r[7] = f2bf(b.w);
    *(bfx8*)dst = r;
}

// global -> LDS direct 16B copy (LDS base wave-uniform; lane*16 implied)
__device__ __forceinline__ void gload_lds16(const void* g, void* l) {
    __builtin_amdgcn_global_load_lds(
        (const __attribute__((address_space(1))) unsigned int*)g,
        (__attribute__((address_space(3))) unsigned int*)l, 16, 0, 0);
}

// ---------------------------------------------------------------------------
// LUT body: lutp[j] = bf16(g[j]) | bf16(g[j+1])<<16, g = exp(fz - max fz)
// ---------------------------------------------------------------------------
__device__ void lut_body(const float* __restrict__ centers, const float* __restrict__ widths,
                         const float* __restrict__ temp, unsigned* __restrict__ lutp) {
    __shared__ float fzb[NLUT];
    __shared__ float red[256];
    __shared__ float cs[48], wsb[48];
    int tid = threadIdx.x;
    if (tid < 48) { cs[tid] = centers[tid]; wsb[tid] = widths[tid]; }
    __syncthreads();
    float invT = 1.0f / temp[0];
    const float step = (LUT_MAX - LUT_MIN) / (float)(NLUT - 1);
    float lmax = -1e30f;
    for (int i = tid; i < NLUT; i += 256) {
        float s = LUT_MIN + step * (float)i;
        float fz = 0.0f;
        #pragma unroll 1
        for (int j = 0; j < 48; j++) {
            float d = s - cs[j];
            float w = wsb[j];
            fz += expf(-(d * d) / (2.0f * w * w));
        }
        fz = fz * (1.0f / 3.0f) * invT;
        fzb[i] = fz;
        lmax = fmaxf(lmax, fz);
    }
    red[tid] = lmax;
    __syncthreads();
    for (int off = 128; off > 0; off >>= 1) {
        if (tid < off) red[tid] = fmaxf(red[tid], red[tid + off]);
        __syncthreads();
    }
    float m = red[0];
    __syncthreads();
    for (int i = tid; i < NLUT; i += 256) fzb[i] = expf(fzb[i] - m);
    __syncthreads();
    for (int i = tid; i < NLUT; i += 256) {
        float g0 = fzb[i];
        float g1 = fzb[(i + 1 < NLUT) ? i + 1 : NLUT - 1];
        unsigned lo = (unsigned short)f2bf(g0);
        unsigned hi = (unsigned short)f2bf(g1);
        lutp[i] = lo | (hi << 16);
    }
}

__global__ void build_lut_pk(const float* centers, const float* widths,
                             const float* temp, unsigned* lutp) {
    lut_body(centers, widths, temp, lutp);
}

// ---------------------------------------------------------------------------
// fp32 -> bf16 cast (fallback path), 8 elems/thread
// ---------------------------------------------------------------------------
__global__ void cast_bf16(const float* __restrict__ src, short* __restrict__ dst, int n8) {
    int i = blockIdx.x * 256 + threadIdx.x;
    if (i < n8) stage8_f32(src + (size_t)i * 8, dst + (size_t)i * 8);
}

// ---------------------------------------------------------------------------
// Fused prep, exact flat grid: [0,6144) inputs, [6144,8192) weights, 8192 LUT
// ---------------------------------------------------------------------------
__global__ void prep_all(const float* q, const float* kin, const float* v,
        const float* wq, const float* wk, const float* wv, const float* wo,
        short* xq, short* xk, short* xv,
        short* bwq, short* bwk, short* bwv, short* bwo,
        const float* centers, const float* widths, const float* temp,
        unsigned* lutp) {
    int bid = blockIdx.x;
    if (bid >= 8192) {
        lut_body(centers, widths, temp, lutp);
        return;
    }
    const float* src; short* dst; int blk;
    if (bid < 6144) {
        int y = bid >> 11; blk = bid & 2047;
        src = (y == 0) ? q : (y == 1) ? kin : v;
        dst = (y == 0) ? xq : (y == 1) ? xk : xv;
    } else {
        int y = (bid - 6144) >> 9; blk = (bid - 6144) & 511;
        src = (y == 0) ? wq : (y == 1) ? wk : (y == 2) ? wv : wo;
        dst = (y == 0) ? bwq : (y == 1) ? bwk : (y == 2) ? bwv : bwo;
    }
    size_t i = (size_t)blk * 256 + threadIdx.x;   // always in range (exact grids)
    stage8_f32(src + i * 8, (short*)dst + i * 8);
}

// ---------------------------------------------------------------------------
// bf16 BT-GEMM, 128x128 tile, BK=32, m97 structure: global_load_lds(16B)
// staging with XOR swizzle, 16 MFMA : 8 ds_read_b128 per k-step.
// C[m,n] = (sum_k A[m,k]*W[n,k] + bias[n]) * scale.
// mode 0: bf16 [B,H,S,DK]; 1: bf16 [B,H,DK,S]; 2: fp32 [M,N]
// ---------------------------------------------------------------------------
struct GemmJob {
    const short* A; const short* W; const float* bias;
    short* obf; float* of32; int mode; float scale;
};

__global__ __launch_bounds__(256, 2) void gemm128(GemmJob j0, GemmJob j1, GemmJob j2) {
    __shared__ __align__(16) short As[128 * 32];   // 8 KB, unpadded + swizzled
    __shared__ __align__(16) short Bs[128 * 32];   // 8 KB
    GemmJob jb = (blockIdx.z == 0) ? j0 : (blockIdx.z == 1) ? j1 : j2;
    int tid = threadIdx.x, wave = tid >> 6, lane = tid & 63, quad = lane >> 4, l15 = lane & 15;
    int m0 = blockIdx.y * 128, n0 = blockIdx.x * 128;
    int wm = (wave >> 1) * 64, wn = (wave & 1) * 64;

    fx4 acc[4][4];
    #pragma unroll
    for (int i = 0; i < 4; i++)
        #pragma unroll
        for (int j = 0; j < 4; j++)
            #pragma unroll
            for (int r = 0; r < 4; r++) acc[i][j][r] = 0.0f;

    int fc = (quad ^ ((l15 >> 1) & 3)) * 8;        // swizzled frag chunk (shorts)

    for (int k0 = 0; k0 < DMODEL; k0 += 32) {
        __syncthreads();
        #pragma unroll
        for (int r = 0; r < 2; r++) {
            int slot = r * 256 + wave * 64 + lane;   // 512 chunks of 16B -> 128x32
            int row = slot >> 2, c = slot & 3, gc = c ^ ((row >> 1) & 3);
            gload_lds16(jb.A + (size_t)(m0 + row) * DMODEL + k0 + gc * 8,
                        &As[(r * 256 + wave * 64) * 8]);
            gload_lds16(jb.W + (size_t)(n0 + row) * DMODEL + k0 + gc * 8,
                        &Bs[(r * 256 + wave * 64) * 8]);
        }
        __syncthreads();
        bfx8 af[4], bfr[4];
        #pragma unroll
        for (int i = 0; i < 4; i++) af[i] = *(const bfx8*)(&As[(wm + i * 16 + l15) * 32 + fc]);
        #pragma unroll
        for (int j = 0; j < 4; j++) bfr[j] = *(const bfx8*)(&Bs[(wn + j * 16 + l15) * 32 + fc]);
        #pragma unroll
        for (int i = 0; i < 4; i++)
            #pragma unroll
            for (int j = 0; j < 4; j++)
                acc[i][j] = __builtin_amdgcn_mfma_f32_16x16x32_bf16(af[i], bfr[j], acc[i][j], 0, 0, 0);
    }

    // epilogue: C/D layout col=lane&15 (n), row=quad*4+reg (m)
    #pragma unroll
    for (int j = 0; j < 4; j++) {
        int n = n0 + wn + j * 16 + l15;
        float bv = jb.bias[n];
        #pragma unroll
        for (int i = 0; i < 4; i++) {
            #pragma unroll
            for (int r = 0; r < 4; r++) {
                int m = m0 + wm + i * 16 + quad * 4 + r;
                float v = (acc[i][j][r] + bv) * jb.scale;
                if (jb.mode == 0) {
                    int b = m >> 11, s = m & 2047, h = n >> 6, dk = n & 63;
                    jb.obf[(((size_t)(b * NHEAD + h)) * S_LEN + s) * DKH + dk] = f2bf(v);
                } else if (jb.mode == 1) {
                    int b = m >> 11, s = m & 2047, h = n >> 6, dk = n & 63;
                    jb.obf[(((size_t)(b * NHEAD + h)) * DKH + dk) * S_LEN + s] = f2bf(v);
                } else {
                    jb.of32[(size_t)m * DMODEL + n] = v;
                }
            }
        }
    }
}

// ---------------------------------------------------------------------------
// Fuzzy flash attention, R5: 32x32x16 MFMA, in-register P.
// Block = 64 q rows of one (b,h); 4 waves: wave (wq, st) owns the
// 32q x 32kv quadrant (wq = q-subtile, st = kv-half of the staged 64-tile).
// S^T = mfma(K, Q): lane (hi,l31) holds S[q=l31][kv=(r&3)+8*(r>>2)+4*hi+st*32].
// Gather+lerp in f32, cvt_pk to bf16 pairs, permlane32_swap -> PV B-frags.
// O^T = mfma(VT, P^T) accumulated in-register; kv halves combined via LDS once.
// ---------------------------------------------------------------------------
__global__ __launch_bounds__(256, 4) void flash_fuzzy(const short* __restrict__ Qb,
        const short* __restrict__ Kb, const short* __restrict__ VTb,
        const unsigned* __restrict__ lutg, short* __restrict__ AO) {
    __shared__ __align__(16) short Ks[64 * 64];     // 8 KB [kv][dk], XOR-swizzled
    __shared__ __align__(16) short Vs[64 * 64];     // 8 KB [dk][kv], XOR-swizzled
    __shared__ unsigned lut[NLUT];                  // 8 KB packed pairs

    int tid = threadIdx.x, wave = tid >> 6, lane = tid & 63;
    int l31 = lane & 31, hi = lane >> 5;
    int wq = wave >> 1, st = wave & 1;
    int q0 = blockIdx.x * 64, bh = blockIdx.y;
    const short* Qp = Qb + (size_t)bh * S_LEN * DKH;
    const short* Kp = Kb + (size_t)bh * S_LEN * DKH;
    const short* Vp = VTb + (size_t)bh * DKH * S_LEN;

    #pragma unroll
    for (int i = tid; i < NLUT / 4; i += 256)
        ((uint4*)lut)[i] = ((const uint4*)lutg)[i];

    // Q as B-operand: lane supplies B[k=hi*8+j][q=l31] = Q[q0+wq*32+l31][k]
    bfx8 aq[4];
    #pragma unroll
    for (int ks = 0; ks < 4; ks++)
        aq[ks] = *(const bfx8*)(Qp + (size_t)(q0 + wq * 32 + l31) * DKH + ks * 16 + hi * 8);

    fx16 oacc[2];
    #pragma unroll
    for (int dt = 0; dt < 2; dt++)
        #pragma unroll
        for (int r = 0; r < 16; r++) oacc[dt][r] = 0.0f;
    float den = 0.0f;

    const float invh = (float)(NLUT - 1) / (LUT_MAX - LUT_MIN);
    const float xoff = -LUT_MIN * invh;

    // staging lane geometry (constant): 512 slots of 16B per buffer, 2 instr/wave
    int srow[2], sgc[2];
    #pragma unroll
    for (int r = 0; r < 2; r++) {
        int slot = (wave * 2 + r) * 64 + lane;
        srow[r] = slot >> 3;
        sgc[r] = (slot & 7) ^ (srow[r] & 7);
    }

    for (int t0 = 0; t0 < S_LEN; t0 += 64) {
        __syncthreads();
        #pragma unroll
        for (int r = 0; r < 2; r++) {
            gload_lds16(Kp + (size_t)(t0 + srow[r]) * DKH + sgc[r] * 8,
                        &Ks[((wave * 2 + r) * 64) * 8]);
            gload_lds16(Vp + (size_t)srow[r] * S_LEN + t0 + sgc[r] * 8,
                        &Vs[((wave * 2 + r) * 64) * 8]);
        }
        __syncthreads();

        // S^T[kv32 (this wave's half)][q32] = K . Q^T over dk=64 (4 k-steps)
        fx16 sac;
        #pragma unroll
        for (int r = 0; r < 16; r++) sac[r] = 0.0f;
        {
            int row = st * 32 + l31;
            #pragma unroll
            for (int ks = 0; ks < 4; ks++) {
                bfx8 kf = *(const bfx8*)(&Ks[row * 64 + (((ks * 2 + hi) ^ (row & 7)) * 8)]);
                sac = __builtin_amdgcn_mfma_f32_32x32x16_bf16(kf, aq[ks], sac, 0, 0, 0);
            }
        }

        // p = g(s): one packed-pair gather + lerp per score; pack pairs to bf16
        unsigned w[8];
        #pragma unroll
        for (int t = 0; t < 8; t++) {
            float pv[2];
            #pragma unroll
            for (int u = 0; u < 2; u++) {
                float s = sac[t * 2 + u];
                float x = fmaf(s, invh, xoff);
                x = fminf(fmaxf(x, 0.0f), (float)(NLUT - 1));
                int j = (int)x;
                float f = x - (float)j;
                unsigned pr = lut[j];
                float v0 = __builtin_bit_cast(float, pr << 16);
                float v1 = __builtin_bit_cast(float, pr & 0xffff0000u);
                pv[u] = fmaf(f, v1 - v0, v0);
            }
            w[t] = cvt_pk_bf16(pv[0], pv[1]);
        }
        // den from the bf16-rounded values (matches the PV numerator exactly)
        #pragma unroll
        for (int t = 0; t < 8; t++) {
            den += __builtin_bit_cast(float, w[t] << 16);
            den += __builtin_bit_cast(float, w[t] & 0xffff0000u);
        }

        // redistribute across lane halves: after swap, w0..w3 = B-frag words
        // 0..3 of PV k-step 0 (kv 0..15 of this half), w4..w7 = k-step 1.
        plane_swap(w[0], w[2]); plane_swap(w[1], w[3]);
        plane_swap(w[4], w[6]); plane_swap(w[5], w[7]);
        ux4 b0v = {w[0], w[1], w[2], w[3]};
        ux4 b1v = {w[4], w[5], w[6], w[7]};
        bfx8 pb0 = __builtin_bit_cast(bfx8, b0v);
        bfx8 pb1 = __builtin_bit_cast(bfx8, b1v);

        // O^T[dk][q] += VT . P^T   (2 dk-tiles x 2 k-steps)
        #pragma unroll
        for (int dt = 0; dt < 2; dt++) {
            int row = dt * 32 + l31;
            bfx8 v0f = *(const bfx8*)(&Vs[row * 64 + (((st * 4 + 0 + hi) ^ (row & 7)) * 8)]);
            bfx8 v1f = *(const bfx8*)(&Vs[row * 64 + (((st * 4 + 2 + hi) ^ (row & 7)) * 8)]);
            oacc[dt] = __builtin_amdgcn_mfma_f32_32x32x16_bf16(v0f, pb0, oacc[dt], 0, 0, 0);
            oacc[dt] = __builtin_amdgcn_mfma_f32_32x32x16_bf16(v1f, pb1, oacc[dt], 0, 0, 0);
        }
    }

    // den: reduce across lane halves (both halves then hold den for q=l31)
    den += __shfl_xor(den, 32);

    // combine kv halves: st=1 waves stash to LDS (Ks/Vs/lut are dead), st=0 finalize
    __syncthreads();
    float* obuf = (wq == 0) ? (float*)Ks : (float*)Vs;   // 8 KB each: 32 regs x 64 lanes
    float* dbuf = (float*)lut;
    if (st == 1) {
        #pragma unroll
        for (int dt = 0; dt < 2; dt++)
            #pragma unroll
            for (int r = 0; r < 16; r++)
                obuf[(dt * 16 + r) * 64 + lane] = oacc[dt][r];
        dbuf[wq * 64 + lane] = den;
    }
    __syncthreads();
    if (st == 0) {
        float dtot = den + dbuf[wq * 64 + lane];
        int b = bh >> 4, h = bh & 15;
        #pragma unroll
        for (int dt = 0; dt < 2; dt++) {
            #pragma unroll
            for (int r = 0; r < 16; r++) {
                float o = oacc[dt][r] + obuf[(dt * 16 + r) * 64 + lane];
                int dk = dt * 32 + (r & 3) + 8 * (r >> 2) + 4 * hi;
                int q = q0 + wq * 32 + l31;
                AO[((size_t)(b * S_LEN + q)) * DMODEL + h * DKH + dk] = f2bf(o / dtot);
            }
        }
    }
}

// ---------------------------------------------------------------------------
extern "C" void kernel_launch(void* const* d_in, const int* in_sizes, int n_in,
                              void* d_out, int out_size, void* d_ws, size_t ws_size,
                              hipStream_t stream) {
    const float* query   = (const float*)d_in[0];
    const float* key_in  = (const float*)d_in[1];
    const float* value   = (const float*)d_in[2];
    const float* w_q     = (const float*)d_in[3];
    const float* b_q     = (const float*)d_in[4];
    const float* w_k     = (const float*)d_in[5];
    const float* b_k     = (const float*)d_in[6];
    const float* w_v     = (const float*)d_in[7];
    const float* b_v     = (const float*)d_in[8];
    const float* w_o     = (const float*)d_in[9];
    const float* b_o     = (const float*)d_in[10];
    const float* centers = (const float*)d_in[11];
    const float* widths  = (const float*)d_in[12];
    const float* temp    = (const float*)d_in[13];

    char* p = (char*)d_ws;
    auto alloc = [&](size_t bytes) -> void* {
        void* r = (void*)p;
        p += (bytes + 255) & ~(size_t)255;
        return r;
    };
    const size_t nBHSD = (size_t)2 * NHEAD * S_LEN * DKH;    // 4.19M elems
    const size_t nW    = (size_t)DMODEL * DMODEL;            // 1.05M elems
    unsigned* lutp = (unsigned*)alloc(NLUT * 4);
    short* Qb  = (short*)alloc(nBHSD * 2);
    short* Kb  = (short*)alloc(nBHSD * 2);
    short* VTb = (short*)alloc(nBHSD * 2);

    char* save = p;
    short* xq  = (short*)alloc(nBHSD * 2);
    short* xk  = (short*)alloc(nBHSD * 2);
    short* xv  = (short*)alloc(nBHSD * 2);
    short* bwq = (short*)alloc(nW * 2);
    short* bwk = (short*)alloc(nW * 2);
    short* bwv = (short*)alloc(nW * 2);
    short* bwo = (short*)alloc(nW * 2);
    bool fused = ((size_t)(p - (char*)d_ws) <= ws_size);

    dim3 blk(256);
    dim3 gq(8, 32, 3), g1(8, 32, 1), fg(32, 32);
    GemmJob JO;

    if (fused) {
        short* AO = xq;   // alias: xq dead after QKV gemm
        prep_all<<<dim3(8193), blk, 0, stream>>>(query, key_in, value, w_q, w_k, w_v, w_o,
                xq, xk, xv, bwq, bwk, bwv, bwo, centers, widths, temp, lutp);
        GemmJob JQ = {xq, bwq, b_q, Qb,  nullptr, 0, 0.125f};   // 1/sqrt(64) folded
        GemmJob JK = {xk, bwk, b_k, Kb,  nullptr, 0, 1.0f};
        GemmJob JV = {xv, bwv, b_v, VTb, nullptr, 1, 1.0f};
        gemm128<<<gq, blk, 0, stream>>>(JQ, JK, JV);
        flash_fuzzy<<<fg, blk, 0, stream>>>(Qb, Kb, VTb, lutp, AO);
        JO = {AO, bwo, b_o, nullptr, (float*)d_out, 2, 1.0f};
        gemm128<<<g1, blk, 0, stream>>>(JO, JO, JO);
    } else {
        // serial fallback: reuse one x-buffer + one w-buffer (~36 MB total)
        p = save;
        short* xf = (short*)alloc(nBHSD * 2);
        short* wb = (short*)alloc(nW * 2);
        short* AO = xf;
        const int n8x = (int)(nBHSD / 8), n8w = (int)(nW / 8);
        dim3 cg((n8x + 255) / 256), cw((n8w + 255) / 256);
        build_lut_pk<<<dim3(1), blk, 0, stream>>>(centers, widths, temp, lutp);
        cast_bf16<<<cg, blk, 0, stream>>>(query, xf, n8x);
        cast_bf16<<<cw, blk, 0, stream>>>(w_q, wb, n8w);
        JO = {xf, wb, b_q, Qb, nullptr, 0, 0.125f};
        gemm128<<<g1, blk, 0, stream>>>(JO, JO, JO);
        cast_bf16<<<cg, blk, 0, stream>>>(key_in, xf, n8x);
        cast_bf16<<<cw, blk, 0, stream>>>(w_k, wb, n8w);
        JO = {xf, wb, b_k, Kb, nullptr, 0, 1.0f};
        gemm128<<<g1, blk, 0, stream>>>(JO, JO, JO);
        cast_bf16<<<cg, blk, 0, stream>>>(value, xf, n8x);
        cast_bf16<<<cw, blk, 0, stream>>>(w_v, wb, n8w);
        JO = {xf, wb, b_v, VTb, nullptr, 1, 1.0f};
        gemm128<<<g1, blk, 0, stream>>>(JO, JO, JO);
        flash_fuzzy<<<fg, blk, 0, stream>>>(Qb, Kb, VTb, lutp, AO);
        cast_bf16<<<cw, blk, 0, stream>>>(w_o, wb, n8w);
        JO = {AO, wb, b_o, nullptr, (float*)d_out, 2, 1.0f};
        gemm128<<<g1, blk, 0, stream>>>(JO, JO, JO);
    }
}